// Round 13
// baseline (183.909 us; speedup 1.0000x reference)
//
#include <hip/hip_runtime.h>

#define DIM 128
#define SCAN_BLK 1024

typedef float f32x4 __attribute__((ext_vector_type(4)));   // native vector for nt builtins

// round-to-nearest-even f32 -> bf16 bits
__device__ __forceinline__ unsigned short bf16rn(float f) {
    unsigned u = __float_as_uint(f);
    u += 0x7fffu + ((u >> 16) & 1u);
    return (unsigned short)(u >> 16);
}

// ---- per-edge degree histogram; atomic return value = rank within node list ----
__global__ void k_count(const int* __restrict__ uidx, const int* __restrict__ iidx,
                        unsigned* __restrict__ cnt, unsigned* __restrict__ ranks,
                        int nu, int ne) {
    int e = blockIdx.x * blockDim.x + threadIdx.x;
    if (e >= ne) return;
    unsigned r0 = atomicAdd(&cnt[uidx[e]], 1u);
    unsigned r1 = atomicAdd(&cnt[nu + iidx[e]], 1u);
    ranks[e] = (r0 << 16) | (r1 & 0xffffu);
}

// ---- two-level scan: 1) per-block inclusive scan + block sums ----
__global__ void k_scan1(const unsigned* __restrict__ cnt, unsigned* __restrict__ incl,
                        unsigned* __restrict__ bsum, int n) {
    __shared__ unsigned part[SCAN_BLK];
    int t = threadIdx.x;
    int j = blockIdx.x * SCAN_BLK + t;
    unsigned v = (j < n) ? cnt[j] : 0u;
    part[t] = v;
    __syncthreads();
    for (int d = 1; d < SCAN_BLK; d <<= 1) {
        unsigned w = (t >= d) ? part[t - d] : 0u;
        __syncthreads();
        part[t] += w;
        __syncthreads();
    }
    if (j < n) incl[j] = part[t];
    if (t == SCAN_BLK - 1) bsum[blockIdx.x] = part[t];
}

// ---- 2) single-block exclusive scan of block sums (nb <= 1024) ----
__global__ void k_scan2(unsigned* __restrict__ bsum, int nb) {
    __shared__ unsigned part[SCAN_BLK];
    int t = threadIdx.x;
    unsigned v = (t < nb) ? bsum[t] : 0u;
    part[t] = v;
    __syncthreads();
    for (int d = 1; d < SCAN_BLK; d <<= 1) {
        unsigned w = (t >= d) ? part[t - d] : 0u;
        __syncthreads();
        part[t] += w;
        __syncthreads();
    }
    if (t < nb) bsum[t] = part[t] - v;   // exclusive prefix
}

// ---- 3) combine: off = incl - cnt + block prefix ----
__global__ void k_scan3(const unsigned* __restrict__ cnt, const unsigned* __restrict__ incl,
                        const unsigned* __restrict__ bsum,
                        unsigned* __restrict__ off, int n) {
    int j = blockIdx.x * blockDim.x + threadIdx.x;
    if (j >= n) return;
    off[j] = incl[j] - cnt[j] + bsum[j / SCAN_BLK];
}

// ---- fused: blocks [0,nbFill) do CSR fill (scattered posted stores, no atomics);
//      blocks [nbFill,..) do per-node dot + bf16 conversion (pure streaming).
//      Safe to co-schedule: fill has no latency-critical L2 reuse (unlike count, R9).
__global__ void k_fill_prep(const int* __restrict__ uidx, const int* __restrict__ iidx,
                            const unsigned* __restrict__ off, const unsigned* __restrict__ ranks,
                            int* __restrict__ nbr,
                            const float* __restrict__ u_emb, const float* __restrict__ i_emb,
                            const float* __restrict__ attn_w, float* __restrict__ sdot,
                            ushort2* __restrict__ bemb,
                            int nu, int n, int ne, int nbFill, int do_bf16) {
    if ((int)blockIdx.x < nbFill) {
        int e = blockIdx.x * blockDim.x + threadIdx.x;
        if (e >= ne) return;
        int u = uidx[e], i = iidx[e];
        unsigned rk = ranks[e];
        nbr[off[u]      + (rk >> 16)]     = nu + i;  // user's neighbor: item (concat idx)
        nbr[off[nu + i] + (rk & 0xffffu)] = u;       // item's neighbor: user
        return;
    }
    int gw = ((blockIdx.x - nbFill) * blockDim.x + threadIdx.x) >> 6;
    int lane = threadIdx.x & 63;
    if (gw >= n) return;
    const bool isU = gw < nu;
    const float2* row = (const float2*)(isU ? u_emb + (size_t)gw * DIM
                                            : i_emb + (size_t)(gw - nu) * DIM);
    const float2* wv  = (const float2*)(isU ? attn_w : attn_w + DIM);
    float2 a = row[lane];
    float2 b = wv[lane];
    float v = a.x * b.x + a.y * b.y;
    #pragma unroll
    for (int off_ = 32; off_; off_ >>= 1) v += __shfl_down(v, off_);
    if (lane == 0) sdot[gw] = v;
    if (do_bf16) {
        ushort2 h;
        h.x = bf16rn(a.x);
        h.y = bf16rn(a.y);
        bemb[(size_t)gw * (DIM / 2) + lane] = h;
    }
}

// ---- persistent-wave accum with cross-node prefetch.
// quarter-wave gathers: 16 lanes per neighbor row, uint4 loads, 4 neighbors/step.
// self rows: nontemporal load (read-once); out rows: nontemporal store (write-once).
__global__ void k_accum_bf16(const float* __restrict__ u_emb, const float* __restrict__ i_emb,
                             const uint4* __restrict__ bemb, const float* __restrict__ sdot,
                             const unsigned* __restrict__ off, const unsigned* __restrict__ cnt,
                             const int* __restrict__ nbr,
                             float* __restrict__ out, int nu, int n) {
    int gw   = (blockIdx.x * blockDim.x + threadIdx.x) >> 6;
    int lane = threadIdx.x & 63;
    int nwav = (gridDim.x * blockDim.x) >> 6;
    int q = lane >> 4, l16 = lane & 15;

    int node = gw;
    if (node >= n) return;

    // prologue: current node's front-end
    unsigned sC = off[node], dC = cnt[node];
    float ssC = sdot[node];
    int oC = 0; float sdC = 0.f;
    {
        unsigned dc = dC < 64u ? dC : 64u;
        if ((unsigned)lane < dc) { oC = nbr[sC + lane]; sdC = sdot[oC]; }
    }

    while (true) {
        // prefetch NEXT node's front-end (off->nbr->sdot chain hides under gather)
        int nnode = node + nwav;
        unsigned sN = 0, dN = 0; float ssN = 0.f; int oN = 0; float sdN = 0.f;
        if (nnode < n) {
            sN = off[nnode]; dN = cnt[nnode]; ssN = sdot[nnode];
            unsigned dn = dN < 64u ? dN : 64u;
            if ((unsigned)lane < dn) { oN = nbr[sN + lane]; sdN = sdot[oN]; }
        }

        float acc[8] = {0.f, 0.f, 0.f, 0.f, 0.f, 0.f, 0.f, 0.f};
        float wsum = 0.f;

        auto doQuad = [&](int oArr, float wArr, int srcIdx, bool active) {
            int   oj = __shfl(oArr, srcIdx);
            float wj = __shfl(wArr, srcIdx);
            if (active) {
                uint4 h = bemb[(size_t)oj * (DIM / 8) + l16];
                wsum += wj;
                acc[0] += wj * __uint_as_float(h.x << 16);
                acc[1] += wj * __uint_as_float(h.x & 0xffff0000u);
                acc[2] += wj * __uint_as_float(h.y << 16);
                acc[3] += wj * __uint_as_float(h.y & 0xffff0000u);
                acc[4] += wj * __uint_as_float(h.z << 16);
                acc[5] += wj * __uint_as_float(h.z & 0xffff0000u);
                acc[6] += wj * __uint_as_float(h.w << 16);
                acc[7] += wj * __uint_as_float(h.w & 0xffff0000u);
            }
        };

        // first chunk (prefetched): weights then 4-wide gather
        unsigned d0 = dC < 64u ? dC : 64u;
        float w = 0.f;
        if ((unsigned)lane < d0) {
            float r = ssC + sdC;
            r = fmaxf(r, 0.2f * r);          // leaky relu, branchless
            w = __expf(r);                    // raw ~ N(0,1): no max shift needed
        }
        unsigned j = 0;
        #pragma unroll 4
        for (; j + 4 <= d0; j += 4) doQuad(oC, w, (int)j + q, true);
        if (j < d0)                 doQuad(oC, w, (int)(j + (unsigned)q), (unsigned)q < d0 - j);

        // tail chunks for d > 64 (rare at this degree distribution)
        for (unsigned base = 64; base < dC; base += 64) {
            unsigned chunk = dC - base; if (chunk > 64) chunk = 64;
            int o2 = 0; float w2 = 0.f;
            if ((unsigned)lane < chunk) {
                o2 = nbr[sC + base + lane];
                float r = ssC + sdot[o2];
                r = fmaxf(r, 0.2f * r);
                w2 = __expf(r);
            }
            unsigned jj = 0;
            for (; jj + 4 <= chunk; jj += 4) doQuad(o2, w2, (int)jj + q, true);
            if (jj < chunk)                  doQuad(o2, w2, (int)(jj + (unsigned)q), (unsigned)q < chunk - jj);
        }

        // combine the 4 quarter-wave partials
        #pragma unroll
        for (int m = 16; m <= 32; m <<= 1) {
            wsum += __shfl_xor(wsum, m);
            #pragma unroll
            for (int k = 0; k < 8; ++k) acc[k] += __shfl_xor(acc[k], m);
        }

        if (q == 0) {
            float inv = 1.f / (wsum + 1e-10f);
            const float* self = (node < nu) ? u_emb + (size_t)node * DIM
                                            : i_emb + (size_t)(node - nu) * DIM;
            const f32x4* sr = (const f32x4*)self;
            f32x4 s0 = __builtin_nontemporal_load(&sr[2 * l16]);
            f32x4 s1 = __builtin_nontemporal_load(&sr[2 * l16 + 1]);
            s0.x += acc[0] * inv; s0.y += acc[1] * inv;
            s0.z += acc[2] * inv; s0.w += acc[3] * inv;
            s1.x += acc[4] * inv; s1.y += acc[5] * inv;
            s1.z += acc[6] * inv; s1.w += acc[7] * inv;
            f32x4* orow = (f32x4*)(out + (size_t)node * DIM);
            __builtin_nontemporal_store(s0, &orow[2 * l16]);
            __builtin_nontemporal_store(s1, &orow[2 * l16 + 1]);
        }

        if (nnode >= n) break;
        node = nnode;
        sC = sN; dC = dN; ssC = ssN; oC = oN; sdC = sdN;
    }
}

// ---- fallback (no bf16 scratch): float2-per-lane, f32 gathers, CSR layout ----
__global__ void k_accum_f32(const float* __restrict__ u_emb, const float* __restrict__ i_emb,
                            const float* __restrict__ sdot,
                            const unsigned* __restrict__ off, const unsigned* __restrict__ cnt,
                            const int* __restrict__ nbr,
                            float* __restrict__ out, int nu, int n) {
    int gw = (blockIdx.x * blockDim.x + threadIdx.x) >> 6;
    int lane = threadIdx.x & 63;
    if (gw >= n) return;
    float sd_self = sdot[gw];
    unsigned s = off[gw];
    unsigned d = cnt[gw];
    float2 acc = make_float2(0.f, 0.f);
    float wsum = 0.f;
    for (unsigned base = 0; base < d; base += 64) {
        unsigned chunk = d - base; if (chunk > 64) chunk = 64;
        int   o = 0;
        float w = 0.f;
        if (lane < (int)chunk) {
            o = nbr[s + base + lane];
            float r = sd_self + sdot[o];
            r = fmaxf(r, 0.2f * r);
            w = __expf(r);
        }
        for (unsigned j = 0; j < chunk; ++j) {
            int   oj = __shfl(o, (int)j);
            float wj = __shfl(w, (int)j);
            const float* base_ = (oj < nu) ? u_emb + (size_t)oj * DIM
                                           : i_emb + (size_t)(oj - nu) * DIM;
            float2 vj = ((const float2*)base_)[lane];
            wsum += wj;
            acc.x += wj * vj.x;
            acc.y += wj * vj.y;
        }
    }
    float inv = 1.f / (wsum + 1e-10f);
    const float* self = (gw < nu) ? u_emb + (size_t)gw * DIM
                                  : i_emb + (size_t)(gw - nu) * DIM;
    float2 sv = ((const float2*)self)[lane];
    sv.x += acc.x * inv;
    sv.y += acc.y * inv;
    ((float2*)(out + (size_t)gw * DIM))[lane] = sv;
}

extern "C" void kernel_launch(void* const* d_in, const int* in_sizes, int n_in,
                              void* d_out, int out_size, void* d_ws, size_t ws_size,
                              hipStream_t stream) {
    const float* u_emb  = (const float*)d_in[0];
    const float* i_emb  = (const float*)d_in[1];
    const int*   edge   = (const int*)d_in[2];
    // d_in[3] = weights, unused by the reference
    const float* attn_w = (const float*)d_in[4];

    const int nu = in_sizes[0] / DIM;
    const int ni = in_sizes[1] / DIM;
    const int ne = in_sizes[3];
    const int n  = nu + ni;

    const int* uidx = edge;
    const int* iidx = edge + ne;

    float* out = (float*)d_out;   // rows [0,nu) = new_u, rows [nu,n) = new_i

    char* ws = (char*)d_ws;
    size_t used = 0;
    auto take = [&](size_t bytes) {
        char* p = ws + used;
        used += (bytes + 15) & ~size_t(15);
        return p;
    };
    float*    sdot  = (float*)   take((size_t)n * sizeof(float));
    unsigned* cnt   = (unsigned*)take((size_t)n * sizeof(unsigned));
    unsigned* off   = (unsigned*)take((size_t)n * sizeof(unsigned));
    unsigned* incl  = (unsigned*)take((size_t)n * sizeof(unsigned));
    unsigned* bsum  = (unsigned*)take((size_t)SCAN_BLK * sizeof(unsigned));
    unsigned* ranks = (unsigned*)take((size_t)ne * sizeof(unsigned));
    int*      nbr   = (int*)     take((size_t)2 * ne * sizeof(int));
    size_t bembBytes = (size_t)n * DIM * 2;          // bf16 concat table (38.4 MB)
    const int do_bf16 = (used + bembBytes <= ws_size) ? 1 : 0;
    void* bemb = do_bf16 ? (void*)take(bembBytes) : nullptr;

    const int nb     = (n + SCAN_BLK - 1) / SCAN_BLK;   // 147 for n=150k
    const int nbFill = (ne + 255) / 256;
    const int nbPrep = (n + 3) / 4;

    // 1. zero degree counters (600 KB, trivial)
    hipMemsetAsync(cnt, 0, (size_t)n * sizeof(unsigned), stream);

    // 2. degree histogram with per-edge ranks (L2-resident atomics, isolated)
    k_count<<<nbFill, 256, 0, stream>>>(uidx, iidx, cnt, ranks, nu, ne);

    // 3. CSR offsets via two-level scan
    k_scan1<<<nb, SCAN_BLK, 0, stream>>>(cnt, incl, bsum, n);
    k_scan2<<<1, SCAN_BLK, 0, stream>>>(bsum, nb);
    k_scan3<<<(n + 255) / 256, 256, 0, stream>>>(cnt, incl, bsum, off, n);

    // 4. fused: CSR fill (posted scattered stores) ∥ prep (dot + bf16, streaming)
    k_fill_prep<<<nbFill + nbPrep, 256, 0, stream>>>(uidx, iidx, off, ranks, nbr,
                                                     u_emb, i_emb, attn_w, sdot,
                                                     (ushort2*)bemb,
                                                     nu, n, ne, nbFill, do_bf16);

    // 5. gather-accumulate: persistent waves, cross-node prefetch, nt self/out traffic
    if (do_bf16)
        k_accum_bf16<<<2048, 256, 0, stream>>>(u_emb, i_emb, (const uint4*)bemb,
                                               sdot, off, cnt, nbr, out, nu, n);
    else
        k_accum_f32<<<(n + 3) / 4, 256, 0, stream>>>(u_emb, i_emb, sdot, off, cnt,
                                                     nbr, out, nu, n);
}

// Round 14
// 173.678 us; speedup vs baseline: 1.0589x; 1.0589x over previous
//
#include <hip/hip_runtime.h>

#define DIM 128
#define SCAN_BLK 1024

// round-to-nearest-even f32 -> bf16 bits
__device__ __forceinline__ unsigned short bf16rn(float f) {
    unsigned u = __float_as_uint(f);
    u += 0x7fffu + ((u >> 16) & 1u);
    return (unsigned short)(u >> 16);
}

// ---- per-node dot + bf16 row conversion; also zeroes cnt (replaces memset) ----
// concatenated node space: rows [0,nu) from u_emb (w_u), [nu,n) from i_emb (w_i)
__global__ void k_prep(const float* __restrict__ u_emb, const float* __restrict__ i_emb,
                       const float* __restrict__ attn_w, float* __restrict__ sdot,
                       ushort2* __restrict__ bemb, unsigned* __restrict__ cnt,
                       int nu, int n, int do_bf16) {
    int tid = blockIdx.x * blockDim.x + threadIdx.x;
    if (tid < n) cnt[tid] = 0u;              // grid has >= n threads (64 per node)
    int gw = tid >> 6;
    int lane = threadIdx.x & 63;
    if (gw >= n) return;
    const bool isU = gw < nu;
    const float2* row = (const float2*)(isU ? u_emb + (size_t)gw * DIM
                                            : i_emb + (size_t)(gw - nu) * DIM);
    const float2* wv  = (const float2*)(isU ? attn_w : attn_w + DIM);
    float2 a = row[lane];
    float2 b = wv[lane];
    float v = a.x * b.x + a.y * b.y;
    #pragma unroll
    for (int off = 32; off; off >>= 1) v += __shfl_down(v, off);
    if (lane == 0) sdot[gw] = v;
    if (do_bf16) {
        ushort2 h;
        h.x = bf16rn(a.x);
        h.y = bf16rn(a.y);
        bemb[(size_t)gw * (DIM / 2) + lane] = h;
    }
}

// ---- per-edge degree histogram; atomic return value = rank within node list ----
__global__ void k_count(const int* __restrict__ uidx, const int* __restrict__ iidx,
                        unsigned* __restrict__ cnt, unsigned* __restrict__ ranks,
                        int nu, int ne) {
    int e = blockIdx.x * blockDim.x + threadIdx.x;
    if (e >= ne) return;
    unsigned r0 = atomicAdd(&cnt[uidx[e]], 1u);
    unsigned r1 = atomicAdd(&cnt[nu + iidx[e]], 1u);
    ranks[e] = (r0 << 16) | (r1 & 0xffffu);
}

// ---- two-level scan: 1) per-block inclusive scan + block sums ----
__global__ void k_scan1(const unsigned* __restrict__ cnt, unsigned* __restrict__ incl,
                        unsigned* __restrict__ bsum, int n) {
    __shared__ unsigned part[SCAN_BLK];
    int t = threadIdx.x;
    int j = blockIdx.x * SCAN_BLK + t;
    unsigned v = (j < n) ? cnt[j] : 0u;
    part[t] = v;
    __syncthreads();
    for (int d = 1; d < SCAN_BLK; d <<= 1) {
        unsigned w = (t >= d) ? part[t - d] : 0u;
        __syncthreads();
        part[t] += w;
        __syncthreads();
    }
    if (j < n) incl[j] = part[t];
    if (t == SCAN_BLK - 1) bsum[blockIdx.x] = part[t];
}

// ---- 2) single-block exclusive scan of block sums (nb <= 1024) ----
__global__ void k_scan2(unsigned* __restrict__ bsum, int nb) {
    __shared__ unsigned part[SCAN_BLK];
    int t = threadIdx.x;
    unsigned v = (t < nb) ? bsum[t] : 0u;
    part[t] = v;
    __syncthreads();
    for (int d = 1; d < SCAN_BLK; d <<= 1) {
        unsigned w = (t >= d) ? part[t - d] : 0u;
        __syncthreads();
        part[t] += w;
        __syncthreads();
    }
    if (t < nb) bsum[t] = part[t] - v;   // exclusive prefix
}

// ---- 3) combine: off = incl - cnt + block prefix ----
__global__ void k_scan3(const unsigned* __restrict__ cnt, const unsigned* __restrict__ incl,
                        const unsigned* __restrict__ bsum,
                        unsigned* __restrict__ off, int n) {
    int j = blockIdx.x * blockDim.x + threadIdx.x;
    if (j >= n) return;
    off[j] = incl[j] - cnt[j] + bsum[j / SCAN_BLK];
}

// ---- per-edge CSR fill: neighbor CONCAT index, rank-addressed (no atomics) ----
__global__ void k_fill(const int* __restrict__ uidx, const int* __restrict__ iidx,
                       const unsigned* __restrict__ off, const unsigned* __restrict__ ranks,
                       int* __restrict__ nbr, int nu, int ne) {
    int e = blockIdx.x * blockDim.x + threadIdx.x;
    if (e >= ne) return;
    int u = uidx[e], i = iidx[e];
    unsigned rk = ranks[e];
    nbr[off[u]      + (rk >> 16)]     = nu + i;  // user's neighbor: item (concat idx)
    nbr[off[nu + i] + (rk & 0xffffu)] = u;       // item's neighbor: user
}

// ---- persistent-wave accum with cross-node prefetch (plain loads/stores;
// nt builtins measured 20 us SLOWER here — they bypass L2 for the self rows).
// quarter-wave gathers: 16 lanes per neighbor row, uint4 loads, 4 neighbors/step.
__global__ void k_accum_bf16(const float* __restrict__ u_emb, const float* __restrict__ i_emb,
                             const uint4* __restrict__ bemb, const float* __restrict__ sdot,
                             const unsigned* __restrict__ off, const unsigned* __restrict__ cnt,
                             const int* __restrict__ nbr,
                             float* __restrict__ out, int nu, int n) {
    int gw   = (blockIdx.x * blockDim.x + threadIdx.x) >> 6;
    int lane = threadIdx.x & 63;
    int nwav = (gridDim.x * blockDim.x) >> 6;
    int q = lane >> 4, l16 = lane & 15;

    int node = gw;
    if (node >= n) return;

    // prologue: current node's front-end
    unsigned sC = off[node], dC = cnt[node];
    float ssC = sdot[node];
    int oC = 0; float sdC = 0.f;
    {
        unsigned dc = dC < 64u ? dC : 64u;
        if ((unsigned)lane < dc) { oC = nbr[sC + lane]; sdC = sdot[oC]; }
    }

    while (true) {
        // prefetch NEXT node's front-end (off->nbr->sdot chain hides under gather)
        int nnode = node + nwav;
        unsigned sN = 0, dN = 0; float ssN = 0.f; int oN = 0; float sdN = 0.f;
        if (nnode < n) {
            sN = off[nnode]; dN = cnt[nnode]; ssN = sdot[nnode];
            unsigned dn = dN < 64u ? dN : 64u;
            if ((unsigned)lane < dn) { oN = nbr[sN + lane]; sdN = sdot[oN]; }
        }

        float acc[8] = {0.f, 0.f, 0.f, 0.f, 0.f, 0.f, 0.f, 0.f};
        float wsum = 0.f;

        auto doQuad = [&](int oArr, float wArr, int srcIdx, bool active) {
            int   oj = __shfl(oArr, srcIdx);
            float wj = __shfl(wArr, srcIdx);
            if (active) {
                uint4 h = bemb[(size_t)oj * (DIM / 8) + l16];
                wsum += wj;
                acc[0] += wj * __uint_as_float(h.x << 16);
                acc[1] += wj * __uint_as_float(h.x & 0xffff0000u);
                acc[2] += wj * __uint_as_float(h.y << 16);
                acc[3] += wj * __uint_as_float(h.y & 0xffff0000u);
                acc[4] += wj * __uint_as_float(h.z << 16);
                acc[5] += wj * __uint_as_float(h.z & 0xffff0000u);
                acc[6] += wj * __uint_as_float(h.w << 16);
                acc[7] += wj * __uint_as_float(h.w & 0xffff0000u);
            }
        };

        // first chunk (prefetched): weights then 4-wide gather
        unsigned d0 = dC < 64u ? dC : 64u;
        float w = 0.f;
        if ((unsigned)lane < d0) {
            float r = ssC + sdC;
            r = fmaxf(r, 0.2f * r);          // leaky relu, branchless
            w = __expf(r);                    // raw ~ N(0,1): no max shift needed
        }
        unsigned j = 0;
        #pragma unroll 4
        for (; j + 4 <= d0; j += 4) doQuad(oC, w, (int)j + q, true);
        if (j < d0)                 doQuad(oC, w, (int)(j + (unsigned)q), (unsigned)q < d0 - j);

        // tail chunks for d > 64 (rare at this degree distribution)
        for (unsigned base = 64; base < dC; base += 64) {
            unsigned chunk = dC - base; if (chunk > 64) chunk = 64;
            int o2 = 0; float w2 = 0.f;
            if ((unsigned)lane < chunk) {
                o2 = nbr[sC + base + lane];
                float r = ssC + sdot[o2];
                r = fmaxf(r, 0.2f * r);
                w2 = __expf(r);
            }
            unsigned jj = 0;
            for (; jj + 4 <= chunk; jj += 4) doQuad(o2, w2, (int)jj + q, true);
            if (jj < chunk)                  doQuad(o2, w2, (int)(jj + (unsigned)q), (unsigned)q < chunk - jj);
        }

        // combine the 4 quarter-wave partials
        #pragma unroll
        for (int m = 16; m <= 32; m <<= 1) {
            wsum += __shfl_xor(wsum, m);
            #pragma unroll
            for (int k = 0; k < 8; ++k) acc[k] += __shfl_xor(acc[k], m);
        }

        if (q == 0) {
            float inv = 1.f / (wsum + 1e-10f);
            const float* self = (node < nu) ? u_emb + (size_t)node * DIM
                                            : i_emb + (size_t)(node - nu) * DIM;
            const float4* sr = (const float4*)self;
            float4 s0 = sr[2 * l16];
            float4 s1 = sr[2 * l16 + 1];
            s0.x += acc[0] * inv; s0.y += acc[1] * inv;
            s0.z += acc[2] * inv; s0.w += acc[3] * inv;
            s1.x += acc[4] * inv; s1.y += acc[5] * inv;
            s1.z += acc[6] * inv; s1.w += acc[7] * inv;
            float4* orow = (float4*)(out + (size_t)node * DIM);
            orow[2 * l16]     = s0;
            orow[2 * l16 + 1] = s1;
        }

        if (nnode >= n) break;
        node = nnode;
        sC = sN; dC = dN; ssC = ssN; oC = oN; sdC = sdN;
    }
}

// ---- fallback (no bf16 scratch): float2-per-lane, f32 gathers, CSR layout ----
__global__ void k_accum_f32(const float* __restrict__ u_emb, const float* __restrict__ i_emb,
                            const float* __restrict__ sdot,
                            const unsigned* __restrict__ off, const unsigned* __restrict__ cnt,
                            const int* __restrict__ nbr,
                            float* __restrict__ out, int nu, int n) {
    int gw = (blockIdx.x * blockDim.x + threadIdx.x) >> 6;
    int lane = threadIdx.x & 63;
    if (gw >= n) return;
    float sd_self = sdot[gw];
    unsigned s = off[gw];
    unsigned d = cnt[gw];
    float2 acc = make_float2(0.f, 0.f);
    float wsum = 0.f;
    for (unsigned base = 0; base < d; base += 64) {
        unsigned chunk = d - base; if (chunk > 64) chunk = 64;
        int   o = 0;
        float w = 0.f;
        if (lane < (int)chunk) {
            o = nbr[s + base + lane];
            float r = sd_self + sdot[o];
            r = fmaxf(r, 0.2f * r);
            w = __expf(r);
        }
        for (unsigned j = 0; j < chunk; ++j) {
            int   oj = __shfl(o, (int)j);
            float wj = __shfl(w, (int)j);
            const float* base_ = (oj < nu) ? u_emb + (size_t)oj * DIM
                                           : i_emb + (size_t)(oj - nu) * DIM;
            float2 vj = ((const float2*)base_)[lane];
            wsum += wj;
            acc.x += wj * vj.x;
            acc.y += wj * vj.y;
        }
    }
    float inv = 1.f / (wsum + 1e-10f);
    const float* self = (gw < nu) ? u_emb + (size_t)gw * DIM
                                  : i_emb + (size_t)(gw - nu) * DIM;
    float2 sv = ((const float2*)self)[lane];
    sv.x += acc.x * inv;
    sv.y += acc.y * inv;
    ((float2*)(out + (size_t)gw * DIM))[lane] = sv;
}

extern "C" void kernel_launch(void* const* d_in, const int* in_sizes, int n_in,
                              void* d_out, int out_size, void* d_ws, size_t ws_size,
                              hipStream_t stream) {
    const float* u_emb  = (const float*)d_in[0];
    const float* i_emb  = (const float*)d_in[1];
    const int*   edge   = (const int*)d_in[2];
    // d_in[3] = weights, unused by the reference
    const float* attn_w = (const float*)d_in[4];

    const int nu = in_sizes[0] / DIM;
    const int ni = in_sizes[1] / DIM;
    const int ne = in_sizes[3];
    const int n  = nu + ni;

    const int* uidx = edge;
    const int* iidx = edge + ne;

    float* out = (float*)d_out;   // rows [0,nu) = new_u, rows [nu,n) = new_i

    char* ws = (char*)d_ws;
    size_t used = 0;
    auto take = [&](size_t bytes) {
        char* p = ws + used;
        used += (bytes + 15) & ~size_t(15);
        return p;
    };
    float*    sdot  = (float*)   take((size_t)n * sizeof(float));
    unsigned* cnt   = (unsigned*)take((size_t)n * sizeof(unsigned));
    unsigned* off   = (unsigned*)take((size_t)n * sizeof(unsigned));
    unsigned* incl  = (unsigned*)take((size_t)n * sizeof(unsigned));
    unsigned* bsum  = (unsigned*)take((size_t)SCAN_BLK * sizeof(unsigned));
    unsigned* ranks = (unsigned*)take((size_t)ne * sizeof(unsigned));
    int*      nbr   = (int*)     take((size_t)2 * ne * sizeof(int));
    size_t bembBytes = (size_t)n * DIM * 2;          // bf16 concat table (38.4 MB)
    const int do_bf16 = (used + bembBytes <= ws_size) ? 1 : 0;
    void* bemb = do_bf16 ? (void*)take(bembBytes) : nullptr;

    const int nb = (n + SCAN_BLK - 1) / SCAN_BLK;   // 147 for n=150k

    // 1. prep: per-node dots + bf16 conversion + cnt zeroing (streaming, no atomics)
    k_prep<<<(n + 3) / 4, 256, 0, stream>>>(u_emb, i_emb, attn_w, sdot,
                                            (ushort2*)bemb, cnt, nu, n, do_bf16);

    // 2. degree histogram with per-edge ranks (L2-resident atomics, isolated)
    k_count<<<(ne + 255) / 256, 256, 0, stream>>>(uidx, iidx, cnt, ranks, nu, ne);

    // 3. CSR offsets via two-level scan
    k_scan1<<<nb, SCAN_BLK, 0, stream>>>(cnt, incl, bsum, n);
    k_scan2<<<1, SCAN_BLK, 0, stream>>>(bsum, nb);
    k_scan3<<<(n + 255) / 256, 256, 0, stream>>>(cnt, incl, bsum, off, n);

    // 4. CSR fill at off+rank (no atomics; isolated from streaming)
    k_fill<<<(ne + 255) / 256, 256, 0, stream>>>(uidx, iidx, off, ranks, nbr, nu, ne);

    // 5. gather-accumulate: persistent waves, cross-node prefetch, plain loads
    if (do_bf16)
        k_accum_bf16<<<2048, 256, 0, stream>>>(u_emb, i_emb, (const uint4*)bemb,
                                               sdot, off, cnt, nbr, out, nu, n);
    else
        k_accum_f32<<<(n + 3) / 4, 256, 0, stream>>>(u_emb, i_emb, sdot, off, cnt,
                                                     nbr, out, nu, n);
}